// Round 5
// baseline (354.715 us; speedup 1.0000x reference)
//
#include <hip/hip_runtime.h>
#include <hip/hip_bf16.h>

#define EMB 300
#define HID 10
#define BATCH 256
#define SEQ 512
#define ROWS (BATCH * SEQ)    // 131072
#define G3 (3 * HID)          // 30
#define KT 10                 // k-tiles of 32 (tile 9 at offset 268, masked weights)
#define XP 308                // padded LDS row stride (floats): 16B-aligned, 2-way banks

typedef __attribute__((ext_vector_type(8))) short short8;   // 8 bf16 = 4 VGPRs
typedef __attribute__((ext_vector_type(4))) float f32x4;    // MFMA C/D

__device__ __forceinline__ float fsig(float x) {
    float e = __builtin_amdgcn_exp2f(-1.4426950408889634f * x);
    return __builtin_amdgcn_rcpf(1.0f + e);
}
__device__ __forceinline__ float ftanh(float x) {
    float e = __builtin_amdgcn_exp2f(2.8853900817779268f * x);
    return fmaf(-2.0f, __builtin_amdgcn_rcpf(1.0f + e), 1.0f);
}
__device__ __forceinline__ float rdlane(float v, int lane) {
    return __int_as_float(__builtin_amdgcn_readlane(__float_as_int(v), lane));
}
__device__ __forceinline__ short bf16_hi(float f) {
    return (short)(__float_as_uint(f) >> 16);
}
__device__ __forceinline__ float bf16_tof(short h) {
    return __uint_as_float(((unsigned)(unsigned short)h) << 16);
}

// ---------------------------------------------------------------------------
// Prep: padded, k-tiled, split-bf16 forward weights wp[32 gates][320 k].
// Tiles 0..8 cover k=0..287; tile 9 covers x-offset 268..299, live only ki>=20
// (k>=288) so nothing is double-counted and x reads stay in-row.
// ---------------------------------------------------------------------------
__global__ void k_prep(const float* __restrict__ w_ih,
                       short* __restrict__ wph, short* __restrict__ wpl) {
    int i = blockIdx.x * 256 + threadIdx.x;
    if (i >= 32 * 320) return;
    int g = i / 320, kk = i % 320;
    int kt = kk >> 5, ki = kk & 31;
    int k = (kt < 9) ? kk : 268 + ki;
    bool live = (g < 30) && ((kt < 9) ? (k < 300) : (ki >= 20));
    float v = live ? w_ih[g * EMB + k] : 0.0f;
    short hi = bf16_hi(v);
    float lo = v - bf16_tof(hi);
    wph[i] = hi;
    wpl[i] = bf16_hi(lo);
}

// ---------------------------------------------------------------------------
// Kernel 1: gi[row][g] = b_ih[g] + x[row]·w_ih[g]  via split-bf16 MFMA.
// v5: stage the whole 32-row x-slab into LDS once (coalesced float4, padded
// stride 308 -> only 2-way bank aliasing), ONE barrier, then 10 unrolled
// k-tiles of ds_read_b128 + MFMA. v4's 2-barriers-per-tile serialized
// staging/compute and blocked hoisting of the L1-resident weight loads.
// ---------------------------------------------------------------------------
__global__ __launch_bounds__(128) void k_gi(const float* __restrict__ x,
                                            const short* __restrict__ wph,
                                            const short* __restrict__ wpl,
                                            const float* __restrict__ b_ih,
                                            float* __restrict__ gi) {
    __shared__ float xs[32 * XP];                 // 39424 B
    const int t    = threadIdx.x;
    const int wave = t >> 6, lane = t & 63;
    const int m = lane & 15, q = lane >> 4;
    const int base = blockIdx.x * 32;             // first of 32 rows
    const int rloc = wave * 16 + m;               // this lane's fragment row

    // ---- stage x slab: 32 rows x 75 float4 = 2400 chunks, coalesced ----
    for (int i = t; i < 32 * 75; i += 128) {
        const int row = i / 75;
        const int piece = i - row * 75;
        const float4 v = *(const float4*)(x + (size_t)(base + row) * EMB + piece * 4);
        *(float4*)(xs + row * XP + piece * 4) = v;
    }
    __syncthreads();

    const float bias0 = b_ih[m];
    const float bias1 = (16 + m < G3) ? b_ih[16 + m] : 0.0f;
    f32x4 acc0 = {bias0, bias0, bias0, bias0};
    f32x4 acc1 = {bias1, bias1, bias1, bias1};

    const int wrow0 = m * 320;
    const int wrow1 = (16 + m) * 320;

#pragma unroll
    for (int kt = 0; kt < KT; kt++) {
        const int k0 = (kt < 9) ? kt * 32 : 268;
        const float* fp = xs + rloc * XP + k0 + q * 8;
        const float4 xa = *(const float4*)fp;
        const float4 xb = *(const float4*)(fp + 4);
        float av[8] = {xa.x, xa.y, xa.z, xa.w, xb.x, xb.y, xb.z, xb.w};

        short8 ah, al;
#pragma unroll
        for (int j = 0; j < 8; j++) {
            short hi = bf16_hi(av[j]);
            ah[j] = hi;
            al[j] = bf16_hi(av[j] - bf16_tof(hi));
        }
        const int wo = kt * 32 + q * 8;
        short8 bh0 = *(const short8*)(wph + wrow0 + wo);
        short8 bl0 = *(const short8*)(wpl + wrow0 + wo);
        short8 bh1 = *(const short8*)(wph + wrow1 + wo);
        short8 bl1 = *(const short8*)(wpl + wrow1 + wo);

        acc0 = __builtin_amdgcn_mfma_f32_16x16x32_bf16(ah, bh0, acc0, 0, 0, 0);
        acc0 = __builtin_amdgcn_mfma_f32_16x16x32_bf16(al, bh0, acc0, 0, 0, 0);
        acc0 = __builtin_amdgcn_mfma_f32_16x16x32_bf16(ah, bl0, acc0, 0, 0, 0);
        acc1 = __builtin_amdgcn_mfma_f32_16x16x32_bf16(ah, bh1, acc1, 0, 0, 0);
        acc1 = __builtin_amdgcn_mfma_f32_16x16x32_bf16(al, bh1, acc1, 0, 0, 0);
        acc1 = __builtin_amdgcn_mfma_f32_16x16x32_bf16(ah, bl1, acc1, 0, 0, 0);
    }
#pragma unroll
    for (int r = 0; r < 4; r++) {
        const size_t row = (size_t)(base + wave * 16 + q * 4 + r);
        gi[row * 32 + m]      = acc0[r];
        gi[row * 32 + 16 + m] = acc1[r];
    }
}

// ---------------------------------------------------------------------------
// Kernel 2: forward recurrence + folded backward step + folded Linear.
// All 256 threads stage the block's gi slice (64 KB) coalesced; then
//   wave 0  : 512-step GRU scan from LDS (depth-4 register ring)
//   wave 1  : concurrently computes the backward-dir single GRU step on
//             x[b,511] (30 gate dots), result passed via the scan-unused
//             col-30 slots of gs (scan only reads cols 0..29)
//   waves 2,3: idle to the final barrier.
// ---------------------------------------------------------------------------
#define PFD 4
__global__ __launch_bounds__(256) void k_scan(const float* __restrict__ gi,
                                              const float* __restrict__ x,
                                              const float* __restrict__ w_hh,
                                              const float* __restrict__ b_hh,
                                              const float* __restrict__ w_ih_b,
                                              const float* __restrict__ b_ih_b,
                                              const float* __restrict__ b_hh_b,
                                              const float* __restrict__ w_lin,
                                              const float* __restrict__ b_lin,
                                              float* __restrict__ out) {
    __shared__ float gs[SEQ * 32];                      // 64 KB exactly
    const int b = blockIdx.x;
    const int t = threadIdx.x;

    const float4* __restrict__ src = (const float4*)(gi + (size_t)b * SEQ * 32);
#pragma unroll
    for (int i = 0; i < (SEQ * 32 / 4) / 256; i++)
        ((float4*)gs)[i * 256 + t] = src[i * 256 + t];
    __syncthreads();

    if (t >= 64 && t < 128) {
        // ---- wave 1: backward direction = one GRU step on x[:,511], h0=0 ----
        const int u = t - 64;
        if (u < G3) {
            const float* __restrict__ xr = x + ((size_t)b * SEQ + (SEQ - 1)) * EMB;
            const float* __restrict__ wr = w_ih_b + (size_t)u * EMB;
            float a0 = 0.f, a1 = 0.f, a2 = 0.f, a3 = 0.f;
            for (int p = 0; p < 75; p += 3) {
                const float4 xv0 = *(const float4*)(xr + p * 4);
                const float4 wv0 = *(const float4*)(wr + p * 4);
                const float4 xv1 = *(const float4*)(xr + p * 4 + 4);
                const float4 wv1 = *(const float4*)(wr + p * 4 + 4);
                const float4 xv2 = *(const float4*)(xr + p * 4 + 8);
                const float4 wv2 = *(const float4*)(wr + p * 4 + 8);
                a0 = fmaf(xv0.x, wv0.x, a0); a1 = fmaf(xv0.y, wv0.y, a1);
                a2 = fmaf(xv0.z, wv0.z, a2); a3 = fmaf(xv0.w, wv0.w, a3);
                a0 = fmaf(xv1.x, wv1.x, a0); a1 = fmaf(xv1.y, wv1.y, a1);
                a2 = fmaf(xv1.z, wv1.z, a2); a3 = fmaf(xv1.w, wv1.w, a3);
                a0 = fmaf(xv2.x, wv2.x, a0); a1 = fmaf(xv2.y, wv2.y, a1);
                a2 = fmaf(xv2.z, wv2.z, a2); a3 = fmaf(xv2.w, wv2.w, a3);
            }
            const float acc = (a0 + a1) + (a2 + a3) + b_ih_b[u];
            const float i_z = __shfl(acc, u + HID, 64);
            const float i_n = __shfl(acc, u + 2 * HID, 64);
            if (u < HID) {
                const float r = fsig(acc + b_hh_b[u]);
                const float z = fsig(i_z + b_hh_b[HID + u]);
                const float n = ftanh(fmaf(r, b_hh_b[2 * HID + u], i_n));
                gs[u * 32 + 30] = (1.0f - z) * n;    // col 30: never read by scan
            }
        }
    } else if (t < 64) {
        // ---- wave 0: the 512-step forward scan ----
        const int j = t;
        const int jc = (j < HID) ? j : HID - 1;

        float wr[HID], wz[HID], wn[HID];
#pragma unroll
        for (int k = 0; k < HID; k++) {
            wr[k] = w_hh[jc * HID + k];
            wz[k] = w_hh[(HID + jc) * HID + k];
            wn[k] = w_hh[(2 * HID + jc) * HID + k];
        }
        const float br = b_hh[jc];
        const float bz = b_hh[HID + jc];
        const float bn = b_hh[2 * HID + jc];

        float pr[PFD], pz[PFD], pn[PFD];
#pragma unroll
        for (int d = 0; d < PFD; d++) {
            pr[d] = gs[d * 32 + jc];
            pz[d] = gs[d * 32 + HID + jc];
            pn[d] = gs[d * 32 + 2 * HID + jc];
        }

        float h = 0.0f;
        float hs[HID];
#pragma unroll
        for (int k = 0; k < HID; k++) hs[k] = 0.0f;

        for (int tt = 0; tt < SEQ; tt += PFD) {
#pragma unroll
            for (int d = 0; d < PFD; d++) {
                const float ir = pr[d], iz = pz[d], in_ = pn[d];

                int tn = tt + d + PFD;
                if (tn >= SEQ) tn = SEQ - 1;
                const float* __restrict__ gp = gs + tn * 32;
                pr[d] = gp[jc];
                pz[d] = gp[HID + jc];
                pn[d] = gp[2 * HID + jc];

                float ar0 = ir + br, ar1 = 0.0f;
                float az0 = iz + bz, az1 = 0.0f;
                float an0 = bn,      an1 = 0.0f;
#pragma unroll
                for (int k = 0; k < 5; k++) {
                    ar0 = fmaf(wr[k], hs[k], ar0);
                    az0 = fmaf(wz[k], hs[k], az0);
                    an0 = fmaf(wn[k], hs[k], an0);
                    ar1 = fmaf(wr[k + 5], hs[k + 5], ar1);
                    az1 = fmaf(wz[k + 5], hs[k + 5], az1);
                    an1 = fmaf(wn[k + 5], hs[k + 5], an1);
                }
                const float r = fsig(ar0 + ar1);
                const float z = fsig(az0 + az1);
                const float n = ftanh(fmaf(r, an0 + an1, in_));
                h = fmaf(z, h - n, n);                  // (1-z)*n + z*h

#pragma unroll
                for (int k = 0; k < HID; k++) hs[k] = rdlane(h, k);
            }
        }
        // stash h for the epilogue in a register that survives the barrier
        // (we just fall through; epilogue below uses h)
        __syncthreads();                                // meet waves 1-3

        const float hbv = gs[jc * 32 + 30];
        const float p = fmaf(w_lin[jc], h, w_lin[HID + jc] * hbv);
        float s = 0.0f;
#pragma unroll
        for (int k = 0; k < HID; k++) s += rdlane(p, k);
        if (j == 0) out[b] = s + b_lin[0];
        return;
    }
    __syncthreads();                                    // waves 1-3 meet wave 0
}

// ---------------------------------------------------------------------------
extern "C" void kernel_launch(void* const* d_in, const int* in_sizes, int n_in,
                              void* d_out, int out_size, void* d_ws, size_t ws_size,
                              hipStream_t stream) {
    const float* x      = (const float*)d_in[0];
    const float* w_ih_f = (const float*)d_in[1];
    const float* w_hh_f = (const float*)d_in[2];
    const float* b_ih_f = (const float*)d_in[3];
    const float* b_hh_f = (const float*)d_in[4];
    const float* w_ih_b = (const float*)d_in[5];
    const float* w_hh_b = (const float*)d_in[6];   // unused: backward is one step, h0=0
    const float* b_ih_b = (const float*)d_in[7];
    const float* b_hh_b = (const float*)d_in[8];
    const float* w_lin  = (const float*)d_in[9];
    const float* b_lin  = (const float*)d_in[10];
    float* out = (float*)d_out;

    short* wph = (short*)d_ws;                          // [32][320] bf16-hi
    short* wpl = wph + 32 * 320;                        // [32][320] bf16-lo
    float* gi  = (float*)((char*)d_ws + 40960);         // [ROWS][32] = 16.78 MB
    (void)w_hh_b; (void)in_sizes; (void)n_in; (void)out_size; (void)ws_size;

    k_prep<<<(32 * 320 + 255) / 256, 256, 0, stream>>>(w_ih_f, wph, wpl);
    k_gi  <<<ROWS / 32, 128, 0, stream>>>(x, wph, wpl, b_ih_f, gi);
    k_scan<<<BATCH, 256, 0, stream>>>(gi, x, w_hh_f, b_hh_f,
                                      w_ih_b, b_ih_b, b_hh_b, w_lin, b_lin, out);
}

// Round 6
// 340.333 us; speedup vs baseline: 1.0423x; 1.0423x over previous
//
#include <hip/hip_runtime.h>
#include <hip/hip_bf16.h>

#define EMB 300
#define HID 10
#define BATCH 256
#define SEQ 512
#define ROWS (BATCH * SEQ)    // 131072
#define G3 (3 * HID)          // 30
#define KT 10                 // k-tiles of 32 (tile 9 at x-offset 268, masked weights)
#define RPB 128               // rows per k_gi block (= threads per block)
#define XSTR 33               // LDS row stride: bank=(t+k)%32 -> 2-way only (free)

__device__ __forceinline__ float fsig(float x) {
    float e = __builtin_amdgcn_exp2f(-1.4426950408889634f * x);
    return __builtin_amdgcn_rcpf(1.0f + e);
}
__device__ __forceinline__ float ftanh(float x) {
    float e = __builtin_amdgcn_exp2f(2.8853900817779268f * x);
    return fmaf(-2.0f, __builtin_amdgcn_rcpf(1.0f + e), 1.0f);
}
__device__ __forceinline__ float rdlane(float v, int lane) {
    return __int_as_float(__builtin_amdgcn_readlane(__float_as_int(v), lane));
}

// ---------------------------------------------------------------------------
// Prep: transposed, k-tiled fp32 weights wt[320 kk][32 g] (wt[kk][g]=w_ih[g][k]).
// Tiles 0..8 cover k=0..287; tile 9 covers x-offset 268..299, live only ki>=20
// (k>=288) so nothing is double-counted and x reads stay in-row. Cols 30,31 = 0.
// Row of 32 g's = 128 B contiguous & wave-uniform per k -> s_load_dwordx16.
// ---------------------------------------------------------------------------
__global__ void k_prep(const float* __restrict__ w_ih, float* __restrict__ wt) {
    int i = blockIdx.x * 256 + threadIdx.x;
    if (i >= 320 * 32) return;
    int kk = i >> 5, g = i & 31;
    int kt = kk >> 5, ki = kk & 31;
    int k = (kt < 9) ? kk : 268 + ki;
    bool live = (g < G3) && ((kt < 9) ? true : (ki >= 20));
    wt[i] = live ? w_ih[g * EMB + k] : 0.0f;
}

// ---------------------------------------------------------------------------
// Kernel 1: gi[row][g] = b_ih[g] + x[row]·w_ih[g]  -- pure fp32 VALU.
// v6 theory: N=30 makes this 2.36 GFLOP = 15 us at vector-fp32 rate; the HBM
// floor is 25 us. MFMA variants (R3-R5) all lost to operand-fetch cost.
// Here weights are WAVE-UNIFORM scalar loads (SMEM pipe, SGPR operand of
// v_fmac) and x is thread-per-row from double-buffered LDS (stride 33,
// conflict-free), staged coalesced. One barrier per k-tile.
// ---------------------------------------------------------------------------
__global__ __launch_bounds__(RPB) void k_gi(const float* __restrict__ x,
                                            const float* __restrict__ wt,
                                            const float* __restrict__ b_ih,
                                            float* __restrict__ gi) {
    __shared__ float xs[2][RPB * XSTR];           // 2 x 16896 B
    const int t = threadIdx.x;
    const int base = blockIdx.x * RPB;
    const int srow = t >> 3;                      // staging: 8 thr cover a row's 128 B
    const int sc4  = (t & 7) * 4;

    float acc[G3];
#pragma unroll
    for (int g = 0; g < G3; g++) acc[g] = b_ih[g];

    const float* __restrict__ xb = x + (size_t)base * EMB;

    // stage tile 0
    float4 pf[8];
#pragma unroll
    for (int j = 0; j < 8; j++)
        pf[j] = *(const float4*)(xb + (size_t)(srow + 16 * j) * EMB + sc4);
#pragma unroll
    for (int j = 0; j < 8; j++) {
        float* d = &xs[0][(srow + 16 * j) * XSTR + sc4];
        d[0] = pf[j].x; d[1] = pf[j].y; d[2] = pf[j].z; d[3] = pf[j].w;
    }
    __syncthreads();

#pragma unroll 1
    for (int kt = 0; kt < KT; kt++) {
        // prefetch next tile while computing this one
        if (kt < 9) {
            const int k0n = (kt < 8) ? (kt + 1) * 32 : 268;
#pragma unroll
            for (int j = 0; j < 8; j++)
                pf[j] = *(const float4*)(xb + (size_t)(srow + 16 * j) * EMB + k0n + sc4);
        }

        const float* __restrict__ bufc = xs[kt & 1] + t * XSTR;
        const float* __restrict__ wk   = wt + kt * 32 * 32;
#pragma unroll 4
        for (int ki = 0; ki < 32; ki++) {
            const float xv = bufc[ki];
            const float* __restrict__ wr = wk + ki * 32;   // uniform -> s_load
#pragma unroll
            for (int g = 0; g < G3; g++)
                acc[g] = fmaf(xv, wr[g], acc[g]);
        }

        if (kt < 9) {
            float* d0 = xs[(kt + 1) & 1];
#pragma unroll
            for (int j = 0; j < 8; j++) {
                float* d = &d0[(srow + 16 * j) * XSTR + sc4];
                d[0] = pf[j].x; d[1] = pf[j].y; d[2] = pf[j].z; d[3] = pf[j].w;
            }
            __syncthreads();
        }
    }

    // store this thread's row: 30 gates + 2 zero pads, 8 float4
    float vals[32];
#pragma unroll
    for (int g = 0; g < G3; g++) vals[g] = acc[g];
    vals[30] = 0.0f; vals[31] = 0.0f;
    float* __restrict__ orow = gi + (size_t)(base + t) * 32;
#pragma unroll
    for (int c = 0; c < 8; c++) {
        float4 o = {vals[c * 4], vals[c * 4 + 1], vals[c * 4 + 2], vals[c * 4 + 3]};
        *(float4*)(orow + c * 4) = o;
    }
}

// ---------------------------------------------------------------------------
// Kernel 2: forward recurrence + folded backward step + folded Linear.
// (unchanged from R5: it was never the top dispatch)
//   all 256 thr stage the block's gi slice (64 KB) coalesced; then
//   wave 0: 512-step GRU scan from LDS (depth-4 register ring)
//   wave 1: backward-dir single GRU step on x[b,511] -> gs col 30
// ---------------------------------------------------------------------------
#define PFD 4
__global__ __launch_bounds__(256) void k_scan(const float* __restrict__ gi,
                                              const float* __restrict__ x,
                                              const float* __restrict__ w_hh,
                                              const float* __restrict__ b_hh,
                                              const float* __restrict__ w_ih_b,
                                              const float* __restrict__ b_ih_b,
                                              const float* __restrict__ b_hh_b,
                                              const float* __restrict__ w_lin,
                                              const float* __restrict__ b_lin,
                                              float* __restrict__ out) {
    __shared__ float gs[SEQ * 32];                      // 64 KB
    const int b = blockIdx.x;
    const int t = threadIdx.x;

    const float4* __restrict__ src = (const float4*)(gi + (size_t)b * SEQ * 32);
#pragma unroll
    for (int i = 0; i < (SEQ * 32 / 4) / 256; i++)
        ((float4*)gs)[i * 256 + t] = src[i * 256 + t];
    __syncthreads();

    if (t >= 64 && t < 128) {
        // ---- wave 1: backward direction = one GRU step on x[:,511], h0=0 ----
        const int u = t - 64;
        if (u < G3) {
            const float* __restrict__ xr = x + ((size_t)b * SEQ + (SEQ - 1)) * EMB;
            const float* __restrict__ wr = w_ih_b + (size_t)u * EMB;
            float a0 = 0.f, a1 = 0.f, a2 = 0.f, a3 = 0.f;
            for (int p = 0; p < 75; p += 3) {
                const float4 xv0 = *(const float4*)(xr + p * 4);
                const float4 wv0 = *(const float4*)(wr + p * 4);
                const float4 xv1 = *(const float4*)(xr + p * 4 + 4);
                const float4 wv1 = *(const float4*)(wr + p * 4 + 4);
                const float4 xv2 = *(const float4*)(xr + p * 4 + 8);
                const float4 wv2 = *(const float4*)(wr + p * 4 + 8);
                a0 = fmaf(xv0.x, wv0.x, a0); a1 = fmaf(xv0.y, wv0.y, a1);
                a2 = fmaf(xv0.z, wv0.z, a2); a3 = fmaf(xv0.w, wv0.w, a3);
                a0 = fmaf(xv1.x, wv1.x, a0); a1 = fmaf(xv1.y, wv1.y, a1);
                a2 = fmaf(xv1.z, wv1.z, a2); a3 = fmaf(xv1.w, wv1.w, a3);
                a0 = fmaf(xv2.x, wv2.x, a0); a1 = fmaf(xv2.y, wv2.y, a1);
                a2 = fmaf(xv2.z, wv2.z, a2); a3 = fmaf(xv2.w, wv2.w, a3);
            }
            const float acc = (a0 + a1) + (a2 + a3) + b_ih_b[u];
            const float i_z = __shfl(acc, u + HID, 64);
            const float i_n = __shfl(acc, u + 2 * HID, 64);
            if (u < HID) {
                const float r = fsig(acc + b_hh_b[u]);
                const float z = fsig(i_z + b_hh_b[HID + u]);
                const float n = ftanh(fmaf(r, b_hh_b[2 * HID + u], i_n));
                gs[u * 32 + 30] = (1.0f - z) * n;       // col 30: never read by scan
            }
        }
    } else if (t < 64) {
        // ---- wave 0: the 512-step forward scan ----
        const int j = t;
        const int jc = (j < HID) ? j : HID - 1;

        float wr[HID], wz[HID], wn[HID];
#pragma unroll
        for (int k = 0; k < HID; k++) {
            wr[k] = w_hh[jc * HID + k];
            wz[k] = w_hh[(HID + jc) * HID + k];
            wn[k] = w_hh[(2 * HID + jc) * HID + k];
        }
        const float br = b_hh[jc];
        const float bz = b_hh[HID + jc];
        const float bn = b_hh[2 * HID + jc];

        float pr[PFD], pz[PFD], pn[PFD];
#pragma unroll
        for (int d = 0; d < PFD; d++) {
            pr[d] = gs[d * 32 + jc];
            pz[d] = gs[d * 32 + HID + jc];
            pn[d] = gs[d * 32 + 2 * HID + jc];
        }

        float h = 0.0f;
        float hs[HID];
#pragma unroll
        for (int k = 0; k < HID; k++) hs[k] = 0.0f;

        for (int tt = 0; tt < SEQ; tt += PFD) {
#pragma unroll
            for (int d = 0; d < PFD; d++) {
                const float ir = pr[d], iz = pz[d], in_ = pn[d];

                int tn = tt + d + PFD;
                if (tn >= SEQ) tn = SEQ - 1;
                const float* __restrict__ gp = gs + tn * 32;
                pr[d] = gp[jc];
                pz[d] = gp[HID + jc];
                pn[d] = gp[2 * HID + jc];

                float ar0 = ir + br, ar1 = 0.0f;
                float az0 = iz + bz, az1 = 0.0f;
                float an0 = bn,      an1 = 0.0f;
#pragma unroll
                for (int k = 0; k < 5; k++) {
                    ar0 = fmaf(wr[k], hs[k], ar0);
                    az0 = fmaf(wz[k], hs[k], az0);
                    an0 = fmaf(wn[k], hs[k], an0);
                    ar1 = fmaf(wr[k + 5], hs[k + 5], ar1);
                    az1 = fmaf(wz[k + 5], hs[k + 5], az1);
                    an1 = fmaf(wn[k + 5], hs[k + 5], an1);
                }
                const float r = fsig(ar0 + ar1);
                const float z = fsig(az0 + az1);
                const float n = ftanh(fmaf(r, an0 + an1, in_));
                h = fmaf(z, h - n, n);                  // (1-z)*n + z*h

#pragma unroll
                for (int k = 0; k < HID; k++) hs[k] = rdlane(h, k);
            }
        }
        __syncthreads();                                // meet waves 1-3

        const float hbv = gs[jc * 32 + 30];
        const float p = fmaf(w_lin[jc], h, w_lin[HID + jc] * hbv);
        float s = 0.0f;
#pragma unroll
        for (int k = 0; k < HID; k++) s += rdlane(p, k);
        if (j == 0) out[b] = s + b_lin[0];
        return;
    }
    __syncthreads();                                    // waves 1-3 meet wave 0
}

// ---------------------------------------------------------------------------
extern "C" void kernel_launch(void* const* d_in, const int* in_sizes, int n_in,
                              void* d_out, int out_size, void* d_ws, size_t ws_size,
                              hipStream_t stream) {
    const float* x      = (const float*)d_in[0];
    const float* w_ih_f = (const float*)d_in[1];
    const float* w_hh_f = (const float*)d_in[2];
    const float* b_ih_f = (const float*)d_in[3];
    const float* b_hh_f = (const float*)d_in[4];
    const float* w_ih_b = (const float*)d_in[5];
    const float* w_hh_b = (const float*)d_in[6];   // unused: backward is one step, h0=0
    const float* b_ih_b = (const float*)d_in[7];
    const float* b_hh_b = (const float*)d_in[8];
    const float* w_lin  = (const float*)d_in[9];
    const float* b_lin  = (const float*)d_in[10];
    float* out = (float*)d_out;

    float* wt = (float*)d_ws;                           // [320][32] fp32 transposed
    float* gi = (float*)((char*)d_ws + 40960);          // [ROWS][32] = 16.78 MB
    (void)w_hh_b; (void)in_sizes; (void)n_in; (void)out_size; (void)ws_size;

    k_prep<<<(320 * 32 + 255) / 256, 256, 0, stream>>>(w_ih_f, wt);
    k_gi  <<<ROWS / RPB, RPB, 0, stream>>>(x, wt, b_ih_f, gi);
    k_scan<<<BATCH, 256, 0, stream>>>(gi, x, w_hh_f, b_hh_f,
                                      w_ih_b, b_ih_b, b_hh_b, w_lin, b_lin, out);
}